// Round 23
// baseline (86.178 us; speedup 1.0000x reference)
//
#include <hip/hip_runtime.h>
#include <hip/hip_bf16.h>

typedef __bf16 bf16_t;
typedef __attribute__((ext_vector_type(8))) __bf16 bf16x8;
typedef __attribute__((ext_vector_type(4))) float f32x4;

#define KDIM 1152
#define NDIM 1152
#define BM 128
#define BN 288
#define BK 32
#define NIT 36                        /* K-steps of 32 */
#define NTILES 4                      /* 1152/288 */
#define AF_STEP 16384                 /* BM*BK*4 bytes (fp32 A tile) */
#define B_STEP 18432                  /* BN*BK*2 bytes per ktile */
#define B_TILE (36 * B_STEP)          /* 663552 B per n-tile panel */

__device__ __forceinline__ void gload_lds16(const void* g, void* l) {
    __builtin_amdgcn_global_load_lds(
        (const __attribute__((address_space(1))) void*)g,
        (__attribute__((address_space(3))) void*)l, 16, 0, 0);
}

// W-fold only (GEMM reads X directly).
// Weff: idx(n,k) = tile*331776 + (k>>5)*9216 + (nin>>4)*512 + ((k>>3)&3)*128
//       + (nin&15)*8 + (k&7)   (tile = n/288, nin = n%288)
__global__ void build_wb(const float* __restrict__ W,
                         const float* __restrict__ bvec,
                         bf16_t* __restrict__ Bm,
                         float* __restrict__ bias)
{
    const int t = blockIdx.x * blockDim.x + threadIdx.x;
    if (t < NDIM) {
        const int o = t / 9, p = t - o * 9;
        bias[t] = bvec[p * 128 + o];
    }
    const int c = t & 127;
    const int o = (t >> 7) & 127;
    const int p = t >> 14;
    if (p >= 9) return;
    const int r = p / 3, cc = p - r * 3;
    float eff[3][3] = {{0.f,0.f,0.f},{0.f,0.f,0.f},{0.f,0.f,0.f}};
    const float* w = W + (size_t)((p * 128 + o) * 128 + c) * 9;
    #pragma unroll
    for (int i = 0; i < 3; ++i) {
        const int a = (2 + r + i) / 3;
        #pragma unroll
        for (int j = 0; j < 3; ++j) {
            const int bb = (2 + cc + j) / 3;
            eff[a][bb] += w[i * 3 + j];
        }
    }
    const int n = o * 9 + p;
    const int tile = n / BN;
    const int nin = n - tile * BN;
    #pragma unroll
    for (int a = 0; a < 3; ++a)
        #pragma unroll
        for (int bb = 0; bb < 3; ++bb) {
            const int k = c * 9 + a * 3 + bb;
            const size_t idx = (size_t)tile * (B_TILE / 2)
                             + (k >> 5) * (B_STEP / 2)
                             + (nin >> 4) * 512 + ((k >> 3) & 3) * 128
                             + (nin & 15) * 8 + (k & 7);
            Bm[idx] = (bf16_t)eff[a][bb];
        }
}

// out[16384,1152] = X(fp32, staged+cvt in-GEMM) * Weff(bf16) + bias.
// CHAMPION (round 20, 74.4us total): BM=128 x BN=288, grid 512 = 2 blocks/CU,
// 4 waves (2m x 2n), wave 64x144, acc 4x9.
// A: fp32 staged DIRECTLY from X via 4 linear gload_lds/thread into a
//    [row][chunk] tile with XOR-swizzle applied on the GLOBAL SOURCE side
//    (rule 21: linear LDS dest, kb = kbx ^ (row&7); read applies same XOR).
//    cvt fp32->bf16 in-register, fused per-mi into the MFMA cluster.
// B: bf16 frag-order panel, 5 gload_lds/thread (5th dummy for tid>=128).
// Ledger: GLD = 9 uniform; enter 9 in flight; stage t+2 (+9); vmcnt(9)
// drains t+1; 0 only at the tail.
__launch_bounds__(256, 2)
__global__ void ind_gemm(const float* __restrict__ X,
                         const bf16_t* __restrict__ Bm,
                         const float* __restrict__ bias,
                         float* __restrict__ out)
{
    __shared__ char Af[2][AF_STEP];
    __shared__ char Bs[2][B_STEP];
    __shared__ char Scrap[1024];

    const int tid = threadIdx.x;
    const int lane = tid & 63;
    const int wid = tid >> 6;
    const int wm = wid >> 1;        // 0..1
    const int wn = wid & 1;         // 0..1

    // XCD swizzle: 512 blocks = 64/XCD; consecutive swz share an m-panel
    // (X panel 590KB fp32, L2-resident) across the 4 n-tiles.
    const int bid = blockIdx.x;
    const int swz = (bid & 7) * 64 + (bid >> 3);
    const int mt = swz >> 2;
    const int nt = swz & 3;
    const int m0 = mt * BM;

    // ---- A staging addressing ----
    // unit v = tid + r*256: row = (tid>>3)+32r, LDS slot kbx = tid&7.
    // source chunk kb = kbx ^ (row&7) = (tid&7) ^ ((tid>>3)&7)  (32r = 0 mod 8)
    const int row0 = tid >> 3;
    const int kb0 = (tid & 7) ^ (row0 & 7);
    const char* asrc = (const char*)(X + (size_t)(m0 + row0) * KDIM + kb0 * 4);
    // per iter T: +T*128 B; per r: +r*147456 B (32 rows)

    // ---- A frag read offsets (XOR on read side) ----
    const int abase = (wm * 64 + (lane & 15)) * 128;  // + mi*2048
    const int g2 = (lane >> 4) * 2;
    const int x0 = ((g2)     ^ (lane & 7)) * 16;
    const int x1 = ((g2 + 1) ^ (lane & 7)) * 16;

    const int fr = (lane >> 4) * 256 + (lane & 15) * 16;
    const char* bpanel = (const char*)Bm + (size_t)nt * B_TILE;

    f32x4 acc[4][9];
    #pragma unroll
    for (int i = 0; i < 4; ++i)
        #pragma unroll
        for (int j = 0; j < 9; ++j)
            acc[i][j] = (f32x4){0.f, 0.f, 0.f, 0.f};

    f32x4 alo[4], ahi[4];
    bf16x8 bfr[9];

    #define GLD(T, BUF) do {                                                \
        const char* sa_ = asrc + (size_t)(T) * 128;                         \
        _Pragma("unroll")                                                   \
        for (int r_ = 0; r_ < 4; ++r_)                                      \
            gload_lds16(sa_ + (size_t)r_ * 147456,                          \
                        &Af[BUF][tid * 16 + r_ * 4096]);                    \
        const char* sb_ = bpanel + (size_t)(T) * B_STEP;                    \
        _Pragma("unroll")                                                   \
        for (int r_ = 0; r_ < 4; ++r_) {                                    \
            const int u_ = (tid + r_ * 256) * 16;                           \
            gload_lds16(sb_ + u_, &Bs[BUF][u_]);                            \
        }                                                                   \
        if (tid < 128) gload_lds16(sb_ + (1024 + tid) * 16,                 \
                                   &Bs[BUF][(1024 + tid) * 16]);            \
        else           gload_lds16(bpanel + tid * 16, Scrap);               \
    } while (0)

    #define RD(CUR) do {                                                    \
        _Pragma("unroll")                                                   \
        for (int mi_ = 0; mi_ < 4; ++mi_) {                                 \
            alo[mi_] = *(const f32x4*)(&Af[CUR][abase + mi_ * 2048 + x0]);  \
            ahi[mi_] = *(const f32x4*)(&Af[CUR][abase + mi_ * 2048 + x1]);  \
        }                                                                   \
        _Pragma("unroll")                                                   \
        for (int j_ = 0; j_ < 9; ++j_)                                      \
            bfr[j_] = *(const bf16x8*)(&Bs[CUR][(wn * 9 + j_) * 1024 + fr]); \
        asm volatile("s_waitcnt lgkmcnt(0)" ::: "memory");                  \
        __builtin_amdgcn_sched_barrier(0);                                  \
        __builtin_amdgcn_s_barrier();                                       \
    } while (0)

    #define MFMA36() do {                                                   \
        __builtin_amdgcn_s_setprio(1);                                      \
        _Pragma("unroll")                                                   \
        for (int mi_ = 0; mi_ < 4; ++mi_) {                                 \
            bf16x8 a_;                                                      \
            _Pragma("unroll")                                               \
            for (int e_ = 0; e_ < 4; ++e_) {                                \
                a_[e_]     = (__bf16)alo[mi_][e_];                          \
                a_[4 + e_] = (__bf16)ahi[mi_][e_];                          \
            }                                                               \
            _Pragma("unroll")                                               \
            for (int j_ = 0; j_ < 9; ++j_)                                  \
                acc[mi_][j_] = __builtin_amdgcn_mfma_f32_16x16x32_bf16(     \
                    a_, bfr[j_], acc[mi_][j_], 0, 0, 0);                    \
        }                                                                   \
        __builtin_amdgcn_s_setprio(0);                                      \
    } while (0)

    #define WAITV(N) do {                                                   \
        asm volatile("s_waitcnt vmcnt(" #N ")" ::: "memory");               \
        __builtin_amdgcn_sched_barrier(0);                                  \
    } while (0)

    // ---- prologue: t0[9] + t1[9] in flight; drain t0, keep t1 flying ----
    GLD(0, 0);
    GLD(1, 1);
    WAITV(9);
    __builtin_amdgcn_s_barrier();

    // steady state: 17 double-iters (t = 0..33)
    #pragma unroll 1
    for (int t2 = 0; t2 < 17; ++t2) {
        const int t = 2 * t2;
        // ---- even iter t (cur=0) ----
        RD(0);                       // 17 ds_read, lgkm0, barrier (frees buf0)
        GLD(t + 2, 0);               // +9 -> 18 in flight
        MFMA36();                    // cvt fused per-mi
        WAITV(9);                    // drains t+1; t+2 stays in flight
        __builtin_amdgcn_s_barrier();
        // ---- odd iter t+1 (cur=1) ----
        RD(1);
        GLD(t + 3, 1);
        MFMA36();
        WAITV(9);
        __builtin_amdgcn_s_barrier();
    }
    // ---- t = 34 (cur=0): no staging; drain all ----
    RD(0);
    MFMA36();
    WAITV(0);
    __builtin_amdgcn_s_barrier();
    // ---- t = 35 (cur=1): compute-only ----
    RD(1);
    MFMA36();

    #undef GLD
    #undef RD
    #undef MFMA36
    #undef WAITV

    // ---- epilogue: C/D col=lane&15, row=(lane>>4)*4+reg ----
    const int orow = (lane >> 4) * 4;
    const int ocol = lane & 15;
    const int gn0 = nt * BN + wn * 144 + ocol;
    #pragma unroll
    for (int ni = 0; ni < 9; ++ni) {
        const float bv = bias[gn0 + ni * 16];
        #pragma unroll
        for (int mi = 0; mi < 4; ++mi) {
            float* po = out + (size_t)(m0 + wm * 64 + mi * 16 + orow) * NDIM
                            + gn0 + ni * 16;
            #pragma unroll
            for (int r = 0; r < 4; ++r)
                po[(size_t)r * NDIM] = acc[mi][ni][r] + bv;
        }
    }
}

extern "C" void kernel_launch(void* const* d_in, const int* in_sizes, int n_in,
                              void* d_out, int out_size, void* d_ws, size_t ws_size,
                              hipStream_t stream)
{
    const float* x  = (const float*)d_in[0];
    const float* W  = (const float*)d_in[1];
    const float* bv = (const float*)d_in[2];
    float* out = (float*)d_out;

    // ws: Bm 2.65 MB | bias 4.6 KB
    bf16_t* Bm   = (bf16_t*)d_ws;
    float*  bias = (float*)((char*)d_ws + (size_t)KDIM * NDIM * sizeof(bf16_t));

    build_wb<<<576, 256, 0, stream>>>(W, bv, Bm, bias);
    ind_gemm<<<512, 256, 0, stream>>>(x, Bm, bias, out);
}

// Round 24
// 84.010 us; speedup vs baseline: 1.0258x; 1.0258x over previous
//
#include <hip/hip_runtime.h>
#include <hip/hip_bf16.h>

typedef __bf16 bf16_t;
typedef __attribute__((ext_vector_type(8))) __bf16 bf16x8;
typedef __attribute__((ext_vector_type(4))) float f32x4;

#define KDIM 1152
#define NDIM 1152
#define BM 128
#define BN 288
#define BK 32
#define NIT 36                        /* K-steps of 32 */
#define NTILES 4                      /* 1152/288 */
#define AF_STEP 16384                 /* BM*BK*4 bytes (fp32 A tile) */
#define B_STEP 18432                  /* BN*BK*2 bytes per ktile */
#define B_TILE (36 * B_STEP)          /* 663552 B per n-tile panel */

__device__ __forceinline__ void gload_lds16(const void* g, void* l) {
    __builtin_amdgcn_global_load_lds(
        (const __attribute__((address_space(1))) void*)g,
        (__attribute__((address_space(3))) void*)l, 16, 0, 0);
}

// W-fold only (GEMM reads X directly).
// Weff: idx(n,k) = tile*331776 + (k>>5)*9216 + (nin>>4)*512 + ((k>>3)&3)*128
//       + (nin&15)*8 + (k&7)   (tile = n/288, nin = n%288)
__global__ void build_wb(const float* __restrict__ W,
                         const float* __restrict__ bvec,
                         bf16_t* __restrict__ Bm,
                         float* __restrict__ bias)
{
    const int t = blockIdx.x * blockDim.x + threadIdx.x;
    if (t < NDIM) {
        const int o = t / 9, p = t - o * 9;
        bias[t] = bvec[p * 128 + o];
    }
    const int c = t & 127;
    const int o = (t >> 7) & 127;
    const int p = t >> 14;
    if (p >= 9) return;
    const int r = p / 3, cc = p - r * 3;
    float eff[3][3] = {{0.f,0.f,0.f},{0.f,0.f,0.f},{0.f,0.f,0.f}};
    const float* w = W + (size_t)((p * 128 + o) * 128 + c) * 9;
    #pragma unroll
    for (int i = 0; i < 3; ++i) {
        const int a = (2 + r + i) / 3;
        #pragma unroll
        for (int j = 0; j < 3; ++j) {
            const int bb = (2 + cc + j) / 3;
            eff[a][bb] += w[i * 3 + j];
        }
    }
    const int n = o * 9 + p;
    const int tile = n / BN;
    const int nin = n - tile * BN;
    #pragma unroll
    for (int a = 0; a < 3; ++a)
        #pragma unroll
        for (int bb = 0; bb < 3; ++bb) {
            const int k = c * 9 + a * 3 + bb;
            const size_t idx = (size_t)tile * (B_TILE / 2)
                             + (k >> 5) * (B_STEP / 2)
                             + (nin >> 4) * 512 + ((k >> 3) & 3) * 128
                             + (nin & 15) * 8 + (k & 7);
            Bm[idx] = (bf16_t)eff[a][bb];
        }
}

// out[16384,1152] = X(fp32, staged+cvt in-GEMM) * Weff(bf16) + bias.
// Champion skeleton (r20) + CONFLICT-FREE A layout:
// BM=128 x BN=288, grid 512 = 2 blocks/CU, 4 waves (2m x 2n), wave 64x144.
// A fp32 tile stored fragment-contiguous: 16B unit (rb,h,g,ri) at byte
//   rb*2048 + h*1024 + g*256 + ri*16, holding row rb*16+ri,
//   floats k = g*8 + h*4 .. +3. Frag reads = contiguous 1KB/wave (0 confl;
//   r20's row-major+XOR layout was 8-way: 2.36M conflict-cycles).
// Staging: linear gload_lds dest (tid*16 + r*4096); per-lane source
//   row=(tid>>7)*16+(tid&15) (+32/r), k-off=((tid>>4)&3)*32+((tid>>6)&1)*16.
// B: bf16 frag-order panel, 5 gload_lds/thread (5th dummy for tid>=128).
// Ledger: GLD = 9 uniform; enter 9 in flight; stage t+2 (+9); vmcnt(9)
// drains t+1; 0 only at the tail.
__launch_bounds__(256, 2)
__global__ void ind_gemm(const float* __restrict__ X,
                         const bf16_t* __restrict__ Bm,
                         const float* __restrict__ bias,
                         float* __restrict__ out)
{
    __shared__ char Af[2][AF_STEP];
    __shared__ char Bs[2][B_STEP];
    __shared__ char Scrap[1024];

    const int tid = threadIdx.x;
    const int lane = tid & 63;
    const int wid = tid >> 6;
    const int wm = wid >> 1;        // 0..1
    const int wn = wid & 1;         // 0..1

    // XCD swizzle: 512 blocks = 64/XCD; consecutive swz share an m-panel
    // (X panel 590KB fp32, L2-resident) across the 4 n-tiles.
    const int bid = blockIdx.x;
    const int swz = (bid & 7) * 64 + (bid >> 3);
    const int mt = swz >> 2;
    const int nt = swz & 3;
    const int m0 = mt * BM;

    // ---- A staging source (frag-contiguous dest mapping) ----
    // unit u = tid + r*256: rb=u>>7, h=(u>>6)&1, g=(u>>4)&3, ri=u&15
    //   -> row = rb*16+ri = (tid>>7)*16+(tid&15) + 32r
    //      k-byte = g*32 + h*16  (from tid bits only)
    const int arow0 = (tid >> 7) * 16 + (tid & 15);
    const int akoff = ((tid >> 4) & 3) * 32 + ((tid >> 6) & 1) * 16;
    const char* asrc = (const char*)X + (size_t)(m0 + arow0) * (KDIM * 4) + akoff;
    // per iter T: +T*128 B; per r: +r*32*KDIM*4 = r*147456 B

    const int fr = (lane >> 4) * 256 + (lane & 15) * 16;
    const char* bpanel = (const char*)Bm + (size_t)nt * B_TILE;

    f32x4 acc[4][9];
    #pragma unroll
    for (int i = 0; i < 4; ++i)
        #pragma unroll
        for (int j = 0; j < 9; ++j)
            acc[i][j] = (f32x4){0.f, 0.f, 0.f, 0.f};

    f32x4 alo[4], ahi[4];
    bf16x8 bfr[9];

    #define GLD(T, BUF) do {                                                \
        const char* sa_ = asrc + (size_t)(T) * 128;                         \
        _Pragma("unroll")                                                   \
        for (int r_ = 0; r_ < 4; ++r_)                                      \
            gload_lds16(sa_ + (size_t)r_ * 147456,                          \
                        &Af[BUF][tid * 16 + r_ * 4096]);                    \
        const char* sb_ = bpanel + (size_t)(T) * B_STEP;                    \
        _Pragma("unroll")                                                   \
        for (int r_ = 0; r_ < 4; ++r_) {                                    \
            const int u_ = (tid + r_ * 256) * 16;                           \
            gload_lds16(sb_ + u_, &Bs[BUF][u_]);                            \
        }                                                                   \
        if (tid < 128) gload_lds16(sb_ + (1024 + tid) * 16,                 \
                                   &Bs[BUF][(1024 + tid) * 16]);            \
        else           gload_lds16(bpanel + tid * 16, Scrap);               \
    } while (0)

    // A frag reads: contiguous 1KB per wave per read -> zero conflicts.
    #define RD(CUR) do {                                                    \
        _Pragma("unroll")                                                   \
        for (int mi_ = 0; mi_ < 4; ++mi_) {                                 \
            alo[mi_] = *(const f32x4*)(&Af[CUR][(wm * 4 + mi_) * 2048 + fr]); \
            ahi[mi_] = *(const f32x4*)(&Af[CUR][(wm * 4 + mi_) * 2048 + 1024 + fr]); \
        }                                                                   \
        _Pragma("unroll")                                                   \
        for (int j_ = 0; j_ < 9; ++j_)                                      \
            bfr[j_] = *(const bf16x8*)(&Bs[CUR][(wn * 9 + j_) * 1024 + fr]); \
        asm volatile("s_waitcnt lgkmcnt(0)" ::: "memory");                  \
        __builtin_amdgcn_sched_barrier(0);                                  \
        __builtin_amdgcn_s_barrier();                                       \
    } while (0)

    #define MFMA36() do {                                                   \
        __builtin_amdgcn_s_setprio(1);                                      \
        _Pragma("unroll")                                                   \
        for (int mi_ = 0; mi_ < 4; ++mi_) {                                 \
            bf16x8 a_;                                                      \
            _Pragma("unroll")                                               \
            for (int e_ = 0; e_ < 4; ++e_) {                                \
                a_[e_]     = (__bf16)alo[mi_][e_];                          \
                a_[4 + e_] = (__bf16)ahi[mi_][e_];                          \
            }                                                               \
            _Pragma("unroll")                                               \
            for (int j_ = 0; j_ < 9; ++j_)                                  \
                acc[mi_][j_] = __builtin_amdgcn_mfma_f32_16x16x32_bf16(     \
                    a_, bfr[j_], acc[mi_][j_], 0, 0, 0);                    \
        }                                                                   \
        __builtin_amdgcn_s_setprio(0);                                      \
    } while (0)

    #define WAITV(N) do {                                                   \
        asm volatile("s_waitcnt vmcnt(" #N ")" ::: "memory");               \
        __builtin_amdgcn_sched_barrier(0);                                  \
    } while (0)

    // ---- prologue: t0[9] + t1[9] in flight; drain t0, keep t1 flying ----
    GLD(0, 0);
    GLD(1, 1);
    WAITV(9);
    __builtin_amdgcn_s_barrier();

    // steady state: 17 double-iters (t = 0..33)
    #pragma unroll 1
    for (int t2 = 0; t2 < 17; ++t2) {
        const int t = 2 * t2;
        // ---- even iter t (cur=0) ----
        RD(0);                       // 17 ds_read, lgkm0, barrier (frees buf0)
        GLD(t + 2, 0);               // +9 -> 18 in flight
        MFMA36();                    // cvt fused per-mi
        WAITV(9);                    // drains t+1; t+2 stays in flight
        __builtin_amdgcn_s_barrier();
        // ---- odd iter t+1 (cur=1) ----
        RD(1);
        GLD(t + 3, 1);
        MFMA36();
        WAITV(9);
        __builtin_amdgcn_s_barrier();
    }
    // ---- t = 34 (cur=0): no staging; drain all ----
    RD(0);
    MFMA36();
    WAITV(0);
    __builtin_amdgcn_s_barrier();
    // ---- t = 35 (cur=1): compute-only ----
    RD(1);
    MFMA36();

    #undef GLD
    #undef RD
    #undef MFMA36
    #undef WAITV

    // ---- epilogue: C/D col=lane&15, row=(lane>>4)*4+reg ----
    const int orow = (lane >> 4) * 4;
    const int ocol = lane & 15;
    const int gn0 = nt * BN + wn * 144 + ocol;
    #pragma unroll
    for (int ni = 0; ni < 9; ++ni) {
        const float bv = bias[gn0 + ni * 16];
        #pragma unroll
        for (int mi = 0; mi < 4; ++mi) {
            float* po = out + (size_t)(m0 + wm * 64 + mi * 16 + orow) * NDIM
                            + gn0 + ni * 16;
            #pragma unroll
            for (int r = 0; r < 4; ++r)
                po[(size_t)r * NDIM] = acc[mi][ni][r] + bv;
        }
    }
}

extern "C" void kernel_launch(void* const* d_in, const int* in_sizes, int n_in,
                              void* d_out, int out_size, void* d_ws, size_t ws_size,
                              hipStream_t stream)
{
    const float* x  = (const float*)d_in[0];
    const float* W  = (const float*)d_in[1];
    const float* bv = (const float*)d_in[2];
    float* out = (float*)d_out;

    // ws: Bm 2.65 MB | bias 4.6 KB
    bf16_t* Bm   = (bf16_t*)d_ws;
    float*  bias = (float*)((char*)d_ws + (size_t)KDIM * NDIM * sizeof(bf16_t));

    build_wb<<<576, 256, 0, stream>>>(W, bv, Bm, bias);
    ind_gemm<<<512, 256, 0, stream>>>(x, Bm, bias, out);
}

// Round 25
// 74.792 us; speedup vs baseline: 1.1522x; 1.1233x over previous
//
#include <hip/hip_runtime.h>
#include <hip/hip_bf16.h>

typedef __bf16 bf16_t;
typedef __attribute__((ext_vector_type(8))) __bf16 bf16x8;
typedef __attribute__((ext_vector_type(4))) float f32x4;

#define KDIM 1152
#define NDIM 1152
#define BM 128
#define BN 288
#define BK 32
#define NIT 36                        /* K-steps of 32 */
#define NTILES 4                      /* 1152/288 */
#define AF_STEP 16384                 /* BM*BK*4 bytes (fp32 A tile) */
#define B_STEP 18432                  /* BN*BK*2 bytes per ktile */
#define B_TILE (36 * B_STEP)          /* 663552 B per n-tile panel */

__device__ __forceinline__ void gload_lds16(const void* g, void* l) {
    __builtin_amdgcn_global_load_lds(
        (const __attribute__((address_space(1))) void*)g,
        (__attribute__((address_space(3))) void*)l, 16, 0, 0);
}

// W-fold only (GEMM reads X directly).
// Weff: idx(n,k) = tile*331776 + (k>>5)*9216 + (nin>>4)*512 + ((k>>3)&3)*128
//       + (nin&15)*8 + (k&7)   (tile = n/288, nin = n%288)
__global__ void build_wb(const float* __restrict__ W,
                         const float* __restrict__ bvec,
                         bf16_t* __restrict__ Bm,
                         float* __restrict__ bias)
{
    const int t = blockIdx.x * blockDim.x + threadIdx.x;
    if (t < NDIM) {
        const int o = t / 9, p = t - o * 9;
        bias[t] = bvec[p * 128 + o];
    }
    const int c = t & 127;
    const int o = (t >> 7) & 127;
    const int p = t >> 14;
    if (p >= 9) return;
    const int r = p / 3, cc = p - r * 3;
    float eff[3][3] = {{0.f,0.f,0.f},{0.f,0.f,0.f},{0.f,0.f,0.f}};
    const float* w = W + (size_t)((p * 128 + o) * 128 + c) * 9;
    #pragma unroll
    for (int i = 0; i < 3; ++i) {
        const int a = (2 + r + i) / 3;
        #pragma unroll
        for (int j = 0; j < 3; ++j) {
            const int bb = (2 + cc + j) / 3;
            eff[a][bb] += w[i * 3 + j];
        }
    }
    const int n = o * 9 + p;
    const int tile = n / BN;
    const int nin = n - tile * BN;
    #pragma unroll
    for (int a = 0; a < 3; ++a)
        #pragma unroll
        for (int bb = 0; bb < 3; ++bb) {
            const int k = c * 9 + a * 3 + bb;
            const size_t idx = (size_t)tile * (B_TILE / 2)
                             + (k >> 5) * (B_STEP / 2)
                             + (nin >> 4) * 512 + ((k >> 3) & 3) * 128
                             + (nin & 15) * 8 + (k & 7);
            Bm[idx] = (bf16_t)eff[a][bb];
        }
}

// out[16384,1152] = X(fp32, staged+cvt in-GEMM) * Weff(bf16) + bias.
// FINAL CHAMPION (round 20, 74.4us best total): BM=128 x BN=288,
// grid 512 = 2 blocks/CU, 4 waves (2m x 2n), wave 64x144, acc 4x9.
// A: fp32 staged DIRECTLY from X via 4 linear gload_lds/thread into a
//    [row][chunk] tile, XOR-swizzle applied on the GLOBAL SOURCE side
//    (rule 21: linear LDS dest, kb = kbx ^ (row&7); read applies same XOR;
//    8-way-spread compromise — frag-contiguous alternative (r24) killed
//    staging coalescing and was net slower). cvt fp32->bf16 in-register,
//    fused per-mi into the MFMA cluster.
// B: bf16 frag-order panel, 5 gload_lds/thread (5th dummy for tid>=128).
// Ledger: GLD = 9 uniform; enter 9 in flight; stage t+2 (+9); vmcnt(9)
// drains t+1; 0 only at the tail.
__launch_bounds__(256, 2)
__global__ void ind_gemm(const float* __restrict__ X,
                         const bf16_t* __restrict__ Bm,
                         const float* __restrict__ bias,
                         float* __restrict__ out)
{
    __shared__ char Af[2][AF_STEP];
    __shared__ char Bs[2][B_STEP];
    __shared__ char Scrap[1024];

    const int tid = threadIdx.x;
    const int lane = tid & 63;
    const int wid = tid >> 6;
    const int wm = wid >> 1;        // 0..1
    const int wn = wid & 1;         // 0..1

    // XCD swizzle: 512 blocks = 64/XCD; consecutive swz share an m-panel
    // (X panel 590KB fp32, L2-resident) across the 4 n-tiles.
    const int bid = blockIdx.x;
    const int swz = (bid & 7) * 64 + (bid >> 3);
    const int mt = swz >> 2;
    const int nt = swz & 3;
    const int m0 = mt * BM;

    // ---- A staging addressing ----
    // unit v = tid + r*256: row = (tid>>3)+32r, LDS slot kbx = tid&7.
    // source chunk kb = kbx ^ (row&7) = (tid&7) ^ ((tid>>3)&7)  (32r = 0 mod 8)
    const int row0 = tid >> 3;
    const int kb0 = (tid & 7) ^ (row0 & 7);
    const char* asrc = (const char*)(X + (size_t)(m0 + row0) * KDIM + kb0 * 4);
    // per iter T: +T*128 B; per r: +r*147456 B (32 rows)

    // ---- A frag read offsets (XOR on read side) ----
    const int abase = (wm * 64 + (lane & 15)) * 128;  // + mi*2048
    const int g2 = (lane >> 4) * 2;
    const int x0 = ((g2)     ^ (lane & 7)) * 16;
    const int x1 = ((g2 + 1) ^ (lane & 7)) * 16;

    const int fr = (lane >> 4) * 256 + (lane & 15) * 16;
    const char* bpanel = (const char*)Bm + (size_t)nt * B_TILE;

    f32x4 acc[4][9];
    #pragma unroll
    for (int i = 0; i < 4; ++i)
        #pragma unroll
        for (int j = 0; j < 9; ++j)
            acc[i][j] = (f32x4){0.f, 0.f, 0.f, 0.f};

    f32x4 alo[4], ahi[4];
    bf16x8 bfr[9];

    #define GLD(T, BUF) do {                                                \
        const char* sa_ = asrc + (size_t)(T) * 128;                         \
        _Pragma("unroll")                                                   \
        for (int r_ = 0; r_ < 4; ++r_)                                      \
            gload_lds16(sa_ + (size_t)r_ * 147456,                          \
                        &Af[BUF][tid * 16 + r_ * 4096]);                    \
        const char* sb_ = bpanel + (size_t)(T) * B_STEP;                    \
        _Pragma("unroll")                                                   \
        for (int r_ = 0; r_ < 4; ++r_) {                                    \
            const int u_ = (tid + r_ * 256) * 16;                           \
            gload_lds16(sb_ + u_, &Bs[BUF][u_]);                            \
        }                                                                   \
        if (tid < 128) gload_lds16(sb_ + (1024 + tid) * 16,                 \
                                   &Bs[BUF][(1024 + tid) * 16]);            \
        else           gload_lds16(bpanel + tid * 16, Scrap);               \
    } while (0)

    #define RD(CUR) do {                                                    \
        _Pragma("unroll")                                                   \
        for (int mi_ = 0; mi_ < 4; ++mi_) {                                 \
            alo[mi_] = *(const f32x4*)(&Af[CUR][abase + mi_ * 2048 + x0]);  \
            ahi[mi_] = *(const f32x4*)(&Af[CUR][abase + mi_ * 2048 + x1]);  \
        }                                                                   \
        _Pragma("unroll")                                                   \
        for (int j_ = 0; j_ < 9; ++j_)                                      \
            bfr[j_] = *(const bf16x8*)(&Bs[CUR][(wn * 9 + j_) * 1024 + fr]); \
        asm volatile("s_waitcnt lgkmcnt(0)" ::: "memory");                  \
        __builtin_amdgcn_sched_barrier(0);                                  \
        __builtin_amdgcn_s_barrier();                                       \
    } while (0)

    #define MFMA36() do {                                                   \
        __builtin_amdgcn_s_setprio(1);                                      \
        _Pragma("unroll")                                                   \
        for (int mi_ = 0; mi_ < 4; ++mi_) {                                 \
            bf16x8 a_;                                                      \
            _Pragma("unroll")                                               \
            for (int e_ = 0; e_ < 4; ++e_) {                                \
                a_[e_]     = (__bf16)alo[mi_][e_];                          \
                a_[4 + e_] = (__bf16)ahi[mi_][e_];                          \
            }                                                               \
            _Pragma("unroll")                                               \
            for (int j_ = 0; j_ < 9; ++j_)                                  \
                acc[mi_][j_] = __builtin_amdgcn_mfma_f32_16x16x32_bf16(     \
                    a_, bfr[j_], acc[mi_][j_], 0, 0, 0);                    \
        }                                                                   \
        __builtin_amdgcn_s_setprio(0);                                      \
    } while (0)

    #define WAITV(N) do {                                                   \
        asm volatile("s_waitcnt vmcnt(" #N ")" ::: "memory");               \
        __builtin_amdgcn_sched_barrier(0);                                  \
    } while (0)

    // ---- prologue: t0[9] + t1[9] in flight; drain t0, keep t1 flying ----
    GLD(0, 0);
    GLD(1, 1);
    WAITV(9);
    __builtin_amdgcn_s_barrier();

    // steady state: 17 double-iters (t = 0..33)
    #pragma unroll 1
    for (int t2 = 0; t2 < 17; ++t2) {
        const int t = 2 * t2;
        // ---- even iter t (cur=0) ----
        RD(0);                       // 17 ds_read, lgkm0, barrier (frees buf0)
        GLD(t + 2, 0);               // +9 -> 18 in flight
        MFMA36();                    // cvt fused per-mi
        WAITV(9);                    // drains t+1; t+2 stays in flight
        __builtin_amdgcn_s_barrier();
        // ---- odd iter t+1 (cur=1) ----
        RD(1);
        GLD(t + 3, 1);
        MFMA36();
        WAITV(9);
        __builtin_amdgcn_s_barrier();
    }
    // ---- t = 34 (cur=0): no staging; drain all ----
    RD(0);
    MFMA36();
    WAITV(0);
    __builtin_amdgcn_s_barrier();
    // ---- t = 35 (cur=1): compute-only ----
    RD(1);
    MFMA36();

    #undef GLD
    #undef RD
    #undef MFMA36
    #undef WAITV

    // ---- epilogue: C/D col=lane&15, row=(lane>>4)*4+reg ----
    const int orow = (lane >> 4) * 4;
    const int ocol = lane & 15;
    const int gn0 = nt * BN + wn * 144 + ocol;
    #pragma unroll
    for (int ni = 0; ni < 9; ++ni) {
        const float bv = bias[gn0 + ni * 16];
        #pragma unroll
        for (int mi = 0; mi < 4; ++mi) {
            float* po = out + (size_t)(m0 + wm * 64 + mi * 16 + orow) * NDIM
                            + gn0 + ni * 16;
            #pragma unroll
            for (int r = 0; r < 4; ++r)
                po[(size_t)r * NDIM] = acc[mi][ni][r] + bv;
        }
    }
}

extern "C" void kernel_launch(void* const* d_in, const int* in_sizes, int n_in,
                              void* d_out, int out_size, void* d_ws, size_t ws_size,
                              hipStream_t stream)
{
    const float* x  = (const float*)d_in[0];
    const float* W  = (const float*)d_in[1];
    const float* bv = (const float*)d_in[2];
    float* out = (float*)d_out;

    // ws: Bm 2.65 MB | bias 4.6 KB
    bf16_t* Bm   = (bf16_t*)d_ws;
    float*  bias = (float*)((char*)d_ws + (size_t)KDIM * NDIM * sizeof(bf16_t));

    build_wb<<<576, 256, 0, stream>>>(W, bv, Bm, bias);
    ind_gemm<<<512, 256, 0, stream>>>(x, Bm, bias, out);
}